// Round 5
// baseline (128.071 us; speedup 1.0000x reference)
//
#include <hip/hip_runtime.h>

#define NB    4
#define DIN_  64
#define DOUT_ 64
#define KN    16
#define NPT   8192
#define CPAD  264   // 256 c-entries + 8 pad shorts; rows 528B (16B-aligned)

typedef __attribute__((ext_vector_type(8))) short short8;
typedef __attribute__((ext_vector_type(4))) float v4f;
typedef const __attribute__((address_space(1))) unsigned int as1_u32;
typedef __attribute__((address_space(3))) unsigned int as3_u32;

__device__ __forceinline__ float bf2f(unsigned short u) {
    unsigned int x = ((unsigned int)u) << 16;
    float f; __builtin_memcpy(&f, &x, 4); return f;
}
__device__ __forceinline__ unsigned short f2bf(float f) {
    unsigned int x; __builtin_memcpy(&x, &f, 4);
    x += 0x7fffu + ((x >> 16) & 1u);   // RNE
    return (unsigned short)(x >> 16);
}

// ---------- prep: 3 jobs in one dispatch (unchanged, proven) ----------
__global__ void k_prep(const float* __restrict__ feat, const float* __restrict__ pos,
                       const float* __restrict__ theta, const float* __restrict__ pbias,
                       unsigned short* __restrict__ ft, float4* __restrict__ pt,
                       unsigned short* __restrict__ tbf) {
    __shared__ float tile[64][65];
    const int bid = blockIdx.x;
    if (bid < 512) {
        int b = bid >> 7, n0 = (bid & 127) << 6;
        int lane = threadIdx.x & 63, w = threadIdx.x >> 6;
#pragma unroll
        for (int r = 0; r < 16; ++r) {
            int i = (r << 2) | w;
            tile[i][lane] = feat[(b*DIN_ + i)*NPT + n0 + lane];
        }
        __syncthreads();
#pragma unroll
        for (int r = 0; r < 16; ++r) {
            int n = (r << 2) | w;
            ft[((size_t)(b*NPT + n0 + n))*DIN_ + lane] = f2bf(tile[lane][n]);
        }
    } else if (bid < 640) {
        int t = (bid - 512)*256 + threadIdx.x;   // 0..32767
        int b = t >> 13, n = t & 8191;
        float4 v;
        v.x = pos[(b*3 + 0)*NPT + n];
        v.y = pos[(b*3 + 1)*NPT + n];
        v.z = pos[(b*3 + 2)*NPT + n];
        v.w = 1.0f;
        pt[t] = v;
    } else {
        int e = (bid - 640)*256 + threadIdx.x;   // 0..2047
        int o = e >> 5, g = e & 31;
        short8 u;
#pragma unroll
        for (int j = 0; j < 8; ++j) {
            int c = g*8 + j;
            float v = (c < 192) ? theta[c*64 + o] : pbias[(c - 192)*64 + o];
            u[j] = (short)f2bf(v);
        }
        *reinterpret_cast<short8*>(tbf + o*256 + g*8) = u;   // 16B aligned
    }
}

// ---------- main (workspace path): DMA-pipelined gather -> Xt -> MFMA ----------
// K split into 8 chunks of 2. Per chunk, per wave: 3 global_load_lds (2 ft-slot
// instrs + 1 pt-slot instr, 16 active lanes) -> counted vmcnt(3) -> barrier ->
// compute previous chunk PURELY from LDS (no global loads => no compiler vmcnt
// can drain the in-flight prefetch). Double-buffered; 2 barriers/chunk.
__global__ __launch_bounds__(256, 4) void k_main_ws(
    const int*            __restrict__ nbr,
    const float*          __restrict__ fbias,
    const unsigned short* __restrict__ ft,
    const float4*         __restrict__ pt,
    const unsigned short* __restrict__ tbf,
    float*                __restrict__ out)
{
    __shared__ __align__(16) unsigned short Xt[32*CPAD];    // 16896 B [q][c]
    __shared__ __align__(16) unsigned short stg[2][64*64];  // 16384 B [buf][slot][64]
    __shared__ __align__(16) float4 ptS[2][64];             //  2048 B [buf][slot]
    __shared__ int    nbs[KN*32];                           //  2048 B [k][q]
    __shared__ float4 pcs[32];                              //   512 B
    // total 37888 B -> 4 blocks/CU

    const int tid  = threadIdx.x;
    const int lane = tid & 63;
    const int w    = tid >> 6;
    const int j16  = lane & 15;
    const int pt2  = lane >> 4;    // stage1: point group; epilogue: quad (kg)

    const int base = blockIdx.x << 5;   // 32 points/block
    const int b    = base >> 13;
    const int nb0  = base & 8191;

    // ---- preamble: nbr slab + center positions ----
#pragma unroll
    for (int r = 0; r < 2; ++r) {
        int idx = tid + (r << 8);            // 0..511
        int k = idx >> 5, c = idx & 31;
        nbs[idx] = nbr[(b*KN + k)*NPT + nb0 + c];
    }
    if (tid < 128)
        ((float*)pcs)[tid] = ((const float*)(pt + b*NPT + nb0))[tid];
    __syncthreads();   // drains preamble VMEM -> clean vmcnt bookkeeping

    const unsigned short* ftb = ft + (((size_t)b) << 19);   // b*NPT*64
    const float4*         ptb = pt + b*NPT;

    const int qq = lane >> 3;          // ft stage: slot-in-group 0..7
    const int fo = (lane & 7) << 3;    // ft stage: feature offset (shorts)

    // per-wave DMA issue for chunk c (ks {2c, 2c+1}) into buffer bi.
    // slot s = kk*32 + q; wave w owns s in [w*16, w*16+16).
    auto ISSUE = [&](int c, int bi) {
#pragma unroll
        for (int j = 0; j < 2; ++j) {
            int s  = (w << 4) + (j << 3) + qq;
            int kk = s >> 5, q = s & 31;
            int id = nbs[(((c << 1) + kk) << 5) + q];
            const unsigned short* gp = ftb + (((size_t)id) << 6) + fo;
            __builtin_amdgcn_global_load_lds(
                (as1_u32*)gp,
                (as3_u32*)&stg[bi][((w << 4) + (j << 3)) << 6],
                16, 0, 0);
        }
        if (lane < 16) {               // 16 active lanes: 16 pt slots, 16B each
            int s  = (w << 4) + lane;
            int kk = s >> 5, q = s & 31;
            int id = nbs[(((c << 1) + kk) << 5) + q];
            __builtin_amdgcn_global_load_lds(
                (as1_u32*)(ptb + id),
                (as3_u32*)&ptS[bi][w << 4],
                16, 0, 0);
        }
    };

    float acc[2][4][4];
#pragma unroll
    for (int ps = 0; ps < 2; ++ps)
#pragma unroll
        for (int p = 0; p < 4; ++p)
#pragma unroll
            for (int j = 0; j < 4; ++j) acc[ps][p][j] = 0.f;

    ISSUE(0, 0);
#pragma unroll
    for (int c = 0; c < 8; ++c) {
        __builtin_amdgcn_sched_barrier(0);
        if (c < 7) ISSUE(c + 1, (c + 1) & 1);
        __builtin_amdgcn_sched_barrier(0);
        if (c < 7) asm volatile("s_waitcnt vmcnt(3)" ::: "memory");
        else       asm volatile("s_waitcnt vmcnt(0)" ::: "memory");
        __builtin_amdgcn_sched_barrier(0);
        __builtin_amdgcn_s_barrier();      // chunk c staged (each wave waited its own)

        const int bi = c & 1;
#pragma unroll
        for (int ps = 0; ps < 2; ++ps) {
            const int q = (w << 3) + (ps << 2) + pt2;
#pragma unroll
            for (int kk = 0; kk < 2; ++kk) {
                const int s = (kk << 5) + q;
                const float4 pg = ptS[bi][s];                       // broadcast
                ushort4 fr = *reinterpret_cast<const ushort4*>(
                    &stg[bi][(s << 6) + (j16 << 2)]);
                float f[4] = { bf2f(fr.x), bf2f(fr.y), bf2f(fr.z), bf2f(fr.w) };
#pragma unroll
                for (int j = 0; j < 4; ++j) {
                    acc[ps][0][j] += pg.x * f[j];
                    acc[ps][1][j] += pg.y * f[j];
                    acc[ps][2][j] += pg.z * f[j];
                    acc[ps][3][j] += f[j];
                }
            }
        }
        __builtin_amdgcn_s_barrier();      // all reads of buf bi done -> reusable
    }

    // ---- center correction + Xt writes ----
#pragma unroll
    for (int ps = 0; ps < 2; ++ps) {
        const int q = (w << 3) + (ps << 2) + pt2;
        const float4 pc = pcs[q];
#pragma unroll
        for (int j = 0; j < 4; ++j) {
            acc[ps][0][j] -= pc.x * acc[ps][3][j];
            acc[ps][1][j] -= pc.y * acc[ps][3][j];
            acc[ps][2][j] -= pc.z * acc[ps][3][j];
        }
#pragma unroll
        for (int p = 0; p < 4; ++p) {
            ushort4 pk;
            pk.x = f2bf(acc[ps][p][0]); pk.y = f2bf(acc[ps][p][1]);
            pk.z = f2bf(acc[ps][p][2]); pk.w = f2bf(acc[ps][p][3]);
            *reinterpret_cast<ushort4*>(&Xt[q*CPAD + (p<<6) + (j16<<2)]) = pk;
        }
    }
    __syncthreads();

    // ---- epilogue: wave w -> o-rows [16w,16w+16); A-frags from L2-hot tbf ----
    const int kg   = pt2;
    const int orow = (w << 4) + j16;
    v4f acc0 = {0.f,0.f,0.f,0.f}, acc1 = {0.f,0.f,0.f,0.f};
#pragma unroll
    for (int ks = 0; ks < 8; ++ks) {
        const int koff = (ks << 5) + (kg << 3);
        short8 a  = *reinterpret_cast<const short8*>(tbf + orow*256 + koff);
        short8 b0 = *reinterpret_cast<const short8*>(&Xt[j16*CPAD + koff]);
        short8 b1 = *reinterpret_cast<const short8*>(&Xt[(16 + j16)*CPAD + koff]);
        acc0 = __builtin_amdgcn_mfma_f32_16x16x32_bf16(a, b0, acc0, 0, 0, 0);
        acc1 = __builtin_amdgcn_mfma_f32_16x16x32_bf16(a, b1, acc1, 0, 0, 0);
    }
#pragma unroll
    for (int r = 0; r < 4; ++r) {
        const int o = (w << 4) + (kg << 2) + r;
        const float fb = fbias[o];
        const size_t rowoff = (size_t)(b*DOUT_ + o)*NPT + nb0;
        out[rowoff + j16]      = acc0[r] + fb;
        out[rowoff + 16 + j16] = acc1[r] + fb;
    }
}

// ---------- fallback (no workspace): R0's direct-gather version ----------
__global__ __launch_bounds__(256, 4) void k_main_f(
    const float* __restrict__ feat, const float* __restrict__ pos,
    const int*   __restrict__ nbr,  const float* __restrict__ theta,
    const float* __restrict__ pbias, const float* __restrict__ fbias,
    float*       __restrict__ out)
{
    __shared__ __align__(16) unsigned short Xt[32*CPAD];
    __shared__ int    nbs[KN*32];
    __shared__ float4 pcs[32];

    const int tid  = threadIdx.x;
    const int lane = tid & 63;
    const int w    = tid >> 6;
    const int j16  = lane & 15;
    const int pt2  = lane >> 4;

    const int base = blockIdx.x << 5;
    const int b    = base >> 13;
    const int nb0  = base & 8191;

#pragma unroll
    for (int r = 0; r < 2; ++r) {
        int idx = tid + (r << 8);
        int k = idx >> 5, c = idx & 31;
        nbs[idx] = nbr[(b*KN + k)*NPT + nb0 + c];
    }
    if (tid < 32) {
        int n = nb0 + tid;
        pcs[tid] = make_float4(pos[(b*3+0)*NPT + n], pos[(b*3+1)*NPT + n],
                               pos[(b*3+2)*NPT + n], 1.0f);
    }
    __syncthreads();

#pragma unroll
    for (int pass = 0; pass < 2; ++pass) {
        const int q = (w << 3) + (pass << 2) + pt2;
        const float4 pc = pcs[q];
        float acc[4][4];
#pragma unroll
        for (int p = 0; p < 4; ++p)
#pragma unroll
            for (int j = 0; j < 4; ++j) acc[p][j] = 0.f;

#pragma unroll 4
        for (int k = 0; k < KN; ++k) {
            const int id = nbs[(k << 5) + q];
            float4 pg; float f[4];
            pg.x = pos[(b*3+0)*NPT + id];
            pg.y = pos[(b*3+1)*NPT + id];
            pg.z = pos[(b*3+2)*NPT + id];
            pg.w = 1.0f;
#pragma unroll
            for (int j = 0; j < 4; ++j)
                f[j] = feat[(b*DIN_ + (j16<<2) + j)*NPT + id];
#pragma unroll
            for (int j = 0; j < 4; ++j) {
                acc[0][j] += pg.x * f[j];
                acc[1][j] += pg.y * f[j];
                acc[2][j] += pg.z * f[j];
                acc[3][j] += f[j];
            }
        }
#pragma unroll
        for (int j = 0; j < 4; ++j) {
            acc[0][j] -= pc.x * acc[3][j];
            acc[1][j] -= pc.y * acc[3][j];
            acc[2][j] -= pc.z * acc[3][j];
        }
#pragma unroll
        for (int p = 0; p < 4; ++p) {
            ushort4 pk;
            pk.x = f2bf(acc[p][0]); pk.y = f2bf(acc[p][1]);
            pk.z = f2bf(acc[p][2]); pk.w = f2bf(acc[p][3]);
            *reinterpret_cast<ushort4*>(&Xt[q*CPAD + (p<<6) + (j16<<2)]) = pk;
        }
    }
    __syncthreads();

    const int kg   = pt2;
    const int orow = (w << 4) + j16;
    v4f acc0 = {0.f,0.f,0.f,0.f}, acc1 = {0.f,0.f,0.f,0.f};
#pragma unroll
    for (int ks = 0; ks < 8; ++ks) {
        const int koff = (ks << 5) + (kg << 3);
        short8 a;
#pragma unroll
        for (int j = 0; j < 8; ++j) {
            int c = koff + j;
            float v = (c < 192) ? theta[c*64 + orow] : pbias[(c - 192)*64 + orow];
            a[j] = (short)f2bf(v);
        }
        short8 b0 = *reinterpret_cast<const short8*>(&Xt[j16*CPAD + koff]);
        short8 b1 = *reinterpret_cast<const short8*>(&Xt[(16 + j16)*CPAD + koff]);
        acc0 = __builtin_amdgcn_mfma_f32_16x16x32_bf16(a, b0, acc0, 0, 0, 0);
        acc1 = __builtin_amdgcn_mfma_f32_16x16x32_bf16(a, b1, acc1, 0, 0, 0);
    }
#pragma unroll
    for (int r = 0; r < 4; ++r) {
        const int o = (w << 4) + (kg << 2) + r;
        const float fb = fbias[o];
        const size_t rowoff = (size_t)(b*DOUT_ + o)*NPT + nb0;
        out[rowoff + j16]      = acc0[r] + fb;
        out[rowoff + 16 + j16] = acc1[r] + fb;
    }
}

extern "C" void kernel_launch(void* const* d_in, const int* in_sizes, int n_in,
                              void* d_out, int out_size, void* d_ws, size_t ws_size,
                              hipStream_t stream) {
    const float* feat  = (const float*)d_in[0];
    const float* pos   = (const float*)d_in[1];
    const int*   nbr   = (const int*)d_in[2];
    const float* theta = (const float*)d_in[3];
    const float* pbias = (const float*)d_in[4];
    const float* fbias = (const float*)d_in[5];
    float* out = (float*)d_out;

    const size_t ft_bytes  = (size_t)NB*NPT*DIN_*2;          // 4 MiB
    const size_t pt_bytes  = (size_t)NB*NPT*sizeof(float4);  // 512 KiB
    const size_t tbf_bytes = (size_t)DOUT_*256*2;            // 32 KiB
    const int n_blocks = (NB*NPT)/32;                        // 1024

    if (ws_size >= ft_bytes + pt_bytes + tbf_bytes) {
        unsigned short* ft  = (unsigned short*)d_ws;
        float4*         pt  = (float4*)((char*)d_ws + ft_bytes);
        unsigned short* tbf = (unsigned short*)((char*)d_ws + ft_bytes + pt_bytes);
        k_prep<<<648, 256, 0, stream>>>(feat, pos, theta, pbias, ft, pt, tbf);
        k_main_ws<<<n_blocks, 256, 0, stream>>>(nbr, fbias, ft, pt, tbf, out);
    } else {
        k_main_f<<<n_blocks, 256, 0, stream>>>(feat, pos, nbr, theta, pbias, fbias, out);
    }
}

// Round 6
// 87.054 us; speedup vs baseline: 1.4712x; 1.4712x over previous
//
#include <hip/hip_runtime.h>

#define NB    4
#define DIN_  64
#define DOUT_ 64
#define KN    16
#define NPT   8192
#define CPAD  264   // 256 c-entries + 8 pad shorts; rows 528B (16B-aligned)

typedef __attribute__((ext_vector_type(8))) short short8;
typedef __attribute__((ext_vector_type(4))) float v4f;

__device__ __forceinline__ float bf2f(unsigned short u) {
    unsigned int x = ((unsigned int)u) << 16;
    float f; __builtin_memcpy(&f, &x, 4); return f;
}
__device__ __forceinline__ unsigned short f2bf(float f) {
    unsigned int x; __builtin_memcpy(&x, &f, 4);
    x += 0x7fffu + ((x >> 16) & 1u);   // RNE
    return (unsigned short)(x >> 16);
}

// ---------- prep: 3 jobs in one dispatch (unchanged, proven) ----------
__global__ void k_prep(const float* __restrict__ feat, const float* __restrict__ pos,
                       const float* __restrict__ theta, const float* __restrict__ pbias,
                       unsigned short* __restrict__ ft, float4* __restrict__ pt,
                       unsigned short* __restrict__ tbf) {
    __shared__ float tile[64][65];
    const int bid = blockIdx.x;
    if (bid < 512) {
        int b = bid >> 7, n0 = (bid & 127) << 6;
        int lane = threadIdx.x & 63, w = threadIdx.x >> 6;
#pragma unroll
        for (int r = 0; r < 16; ++r) {
            int i = (r << 2) | w;
            tile[i][lane] = feat[(b*DIN_ + i)*NPT + n0 + lane];
        }
        __syncthreads();
#pragma unroll
        for (int r = 0; r < 16; ++r) {
            int n = (r << 2) | w;
            ft[((size_t)(b*NPT + n0 + n))*DIN_ + lane] = f2bf(tile[lane][n]);
        }
    } else if (bid < 640) {
        int t = (bid - 512)*256 + threadIdx.x;   // 0..32767
        int b = t >> 13, n = t & 8191;
        float4 v;
        v.x = pos[(b*3 + 0)*NPT + n];
        v.y = pos[(b*3 + 1)*NPT + n];
        v.z = pos[(b*3 + 2)*NPT + n];
        v.w = 1.0f;
        pt[t] = v;
    } else {
        int e = (bid - 640)*256 + threadIdx.x;   // 0..2047
        int o = e >> 5, g = e & 31;
        short8 u;
#pragma unroll
        for (int j = 0; j < 8; ++j) {
            int c = g*8 + j;
            float v = (c < 192) ? theta[c*64 + o] : pbias[(c - 192)*64 + o];
            u[j] = (short)f2bf(v);
        }
        *reinterpret_cast<short8*>(tbf + o*256 + g*8) = u;   // 16B aligned
    }
}

// ---------- main: R0 structure + pt-broadcast dedup via per-lane-k prefetch ----------
// Lane-request accounting: old inner loop had 16 lanes all loading the SAME
// pt[id] float4 per (k, point) -> 16x redundant TA lane-requests. Now lane
// (pt2, j16) loads pt for (its point q, k=j16) ONCE per pass into ptk[q][k]
// (wave-internal LDS, no barrier), and the k-loop reads it as an LDS
// broadcast. pt lane-reqs drop 16x; ft gathers unchanged (proven layout).
template<bool USE_WS>
__global__ __launch_bounds__(256, 4) void k_main(
    const float*          __restrict__ feat,
    const float*          __restrict__ pos,
    const int*            __restrict__ nbr,
    const float*          __restrict__ theta,
    const float*          __restrict__ pbias,
    const float*          __restrict__ fbias,
    const unsigned short* __restrict__ ft,
    const float4*         __restrict__ pt,
    const unsigned short* __restrict__ tbf,
    float*                __restrict__ out)
{
    __shared__ __align__(16) unsigned short Xt[32*CPAD];  // 16896 B  [q][c]
    __shared__ int    nbs[KN*32];                         // 2048 B   [k][q]
    __shared__ float4 pcs[32];                            // 512 B
    __shared__ float4 ptk[32][16];                        // 8192 B   [q][k]
    // total 27648 B -> 4 blocks/CU

    const int tid  = threadIdx.x;
    const int lane = tid & 63;
    const int w    = tid >> 6;
    const int j16  = lane & 15;
    const int pt2  = lane >> 4;    // stage1: which of 4 points; epilogue: quad (kg)

    const int base = blockIdx.x << 5;   // 32 points/block; 8192%32==0 -> single batch
    const int b    = base >> 13;
    const int nb0  = base & 8191;

    // ---- cooperative preamble: nbr slab + center positions ----
#pragma unroll
    for (int r = 0; r < 2; ++r) {
        int idx = tid + (r << 8);            // 0..511
        int k = idx >> 5, c = idx & 31;
        nbs[idx] = nbr[(b*KN + k)*NPT + nb0 + c];
    }
    if (tid < 128) {
        if (USE_WS) {
            ((float*)pcs)[tid] = ((const float*)(pt + b*NPT + nb0))[tid];
        } else if (tid < 32) {
            int n = nb0 + tid;
            pcs[tid] = make_float4(pos[(b*3+0)*NPT + n], pos[(b*3+1)*NPT + n],
                                   pos[(b*3+2)*NPT + n], 1.0f);
        }
    }
    __syncthreads();

    const unsigned short* ftb = ft + (((size_t)b) << 19);   // b*NPT*64
    const float4*         ptb = pt + b*NPT;

    // ---- stage 1: 2 passes x 4 points per wave; lane owns (point, 4-feature chunk) ----
#pragma unroll
    for (int pass = 0; pass < 2; ++pass) {
        const int q = (w << 3) + (pass << 2) + pt2;
        const float4 pc = pcs[q];

        if (USE_WS) {
            // per-pass pt prefetch: lane (pt2 -> q, j16 -> k). One float4 load
            // per lane covers all 16 ks of this wave's 4 points. Same-wave
            // write->read (q depends only on own w) => waitcnt only, no barrier.
            const int idp = nbs[(j16 << 5) + q];
            ptk[q][j16] = ptb[idp];
        }

        float acc[4][4];
#pragma unroll
        for (int p = 0; p < 4; ++p)
#pragma unroll
            for (int j = 0; j < 4; ++j) acc[p][j] = 0.f;

#pragma unroll 4
        for (int k = 0; k < KN; ++k) {
            const int id = nbs[(k << 5) + q];      // LDS broadcast (16 lanes share)
            float4 pg; float f[4];
            if (USE_WS) {
                pg = ptk[q][k];                    // LDS broadcast (was 16 VMEM reqs)
                ushort4 fr = *reinterpret_cast<const ushort4*>(
                    ftb + (((size_t)id) << 6) + (j16 << 2));
                f[0]=bf2f(fr.x); f[1]=bf2f(fr.y); f[2]=bf2f(fr.z); f[3]=bf2f(fr.w);
            } else {
                pg.x = pos[(b*3+0)*NPT + id];
                pg.y = pos[(b*3+1)*NPT + id];
                pg.z = pos[(b*3+2)*NPT + id];
                pg.w = 1.0f;
#pragma unroll
                for (int j = 0; j < 4; ++j)
                    f[j] = feat[(b*DIN_ + (j16<<2) + j)*NPT + id];
            }
#pragma unroll
            for (int j = 0; j < 4; ++j) {
                acc[0][j] += pg.x * f[j];
                acc[1][j] += pg.y * f[j];
                acc[2][j] += pg.z * f[j];
                acc[3][j] += f[j];
            }
        }
        // center correction: M_p -= pc_p * S
#pragma unroll
        for (int j = 0; j < 4; ++j) {
            acc[0][j] -= pc.x * acc[3][j];
            acc[1][j] -= pc.y * acc[3][j];
            acc[2][j] -= pc.z * acc[3][j];
        }
        // write X[q][c], c = p*64 + j16*4 + j  (bf16)
#pragma unroll
        for (int p = 0; p < 4; ++p) {
            ushort4 pk;
            pk.x = f2bf(acc[p][0]); pk.y = f2bf(acc[p][1]);
            pk.z = f2bf(acc[p][2]); pk.w = f2bf(acc[p][3]);
            *reinterpret_cast<ushort4*>(&Xt[q*CPAD + (p<<6) + (j16<<2)]) = pk;
        }
    }
    __syncthreads();

    // ---- epilogue: wave w -> o-rows [16w,16w+16); A-frags straight from L2-hot tbf ----
    const int kg   = pt2;                 // mfma quad
    const int orow = (w << 4) + j16;      // A: m = lane&15
    v4f acc0 = {0.f,0.f,0.f,0.f}, acc1 = {0.f,0.f,0.f,0.f};
#pragma unroll
    for (int ks = 0; ks < 8; ++ks) {
        const int koff = (ks << 5) + (kg << 3);   // k = quad*8 + j
        short8 a;
        if (USE_WS) {
            a = *reinterpret_cast<const short8*>(tbf + orow*256 + koff);
        } else {
#pragma unroll
            for (int j = 0; j < 8; ++j) {
                int c = koff + j;
                float v = (c < 192) ? theta[c*64 + orow] : pbias[(c - 192)*64 + orow];
                a[j] = (short)f2bf(v);
            }
        }
        short8 b0 = *reinterpret_cast<const short8*>(&Xt[j16*CPAD + koff]);
        short8 b1 = *reinterpret_cast<const short8*>(&Xt[(16 + j16)*CPAD + koff]);
        acc0 = __builtin_amdgcn_mfma_f32_16x16x32_bf16(a, b0, acc0, 0, 0, 0);
        acc1 = __builtin_amdgcn_mfma_f32_16x16x32_bf16(a, b1, acc1, 0, 0, 0);
    }
    // C/D: col=lane&15 (point), row=quad*4+reg (o)
#pragma unroll
    for (int r = 0; r < 4; ++r) {
        const int o = (w << 4) + (kg << 2) + r;
        const float fb = fbias[o];
        const size_t rowoff = (size_t)(b*DOUT_ + o)*NPT + nb0;
        out[rowoff + j16]      = acc0[r] + fb;
        out[rowoff + 16 + j16] = acc1[r] + fb;
    }
}

extern "C" void kernel_launch(void* const* d_in, const int* in_sizes, int n_in,
                              void* d_out, int out_size, void* d_ws, size_t ws_size,
                              hipStream_t stream) {
    const float* feat  = (const float*)d_in[0];
    const float* pos   = (const float*)d_in[1];
    const int*   nbr   = (const int*)d_in[2];
    const float* theta = (const float*)d_in[3];
    const float* pbias = (const float*)d_in[4];
    const float* fbias = (const float*)d_in[5];
    float* out = (float*)d_out;

    const size_t ft_bytes  = (size_t)NB*NPT*DIN_*2;          // 4 MiB
    const size_t pt_bytes  = (size_t)NB*NPT*sizeof(float4);  // 512 KiB
    const size_t tbf_bytes = (size_t)DOUT_*256*2;            // 32 KiB
    const int n_blocks = (NB*NPT)/32;                        // 1024

    if (ws_size >= ft_bytes + pt_bytes + tbf_bytes) {
        unsigned short* ft  = (unsigned short*)d_ws;
        float4*         pt  = (float4*)((char*)d_ws + ft_bytes);
        unsigned short* tbf = (unsigned short*)((char*)d_ws + ft_bytes + pt_bytes);
        k_prep<<<648, 256, 0, stream>>>(feat, pos, theta, pbias, ft, pt, tbf);
        k_main<true><<<n_blocks, 256, 0, stream>>>(feat, pos, nbr, theta, pbias, fbias,
                                                   ft, pt, tbf, out);
    } else {
        k_main<false><<<n_blocks, 256, 0, stream>>>(feat, pos, nbr, theta, pbias, fbias,
                                                    (const unsigned short*)feat,
                                                    (const float4*)feat,
                                                    (const unsigned short*)feat, out);
    }
}

// Round 7
// 86.397 us; speedup vs baseline: 1.4824x; 1.0076x over previous
//
#include <hip/hip_runtime.h>

#define NB    4
#define DIN_  64
#define DOUT_ 64
#define KN    16
#define NPT   8192
#define CPAD  264   // 256 c-entries + 8 pad shorts; rows 528B (16B-aligned)

typedef __attribute__((ext_vector_type(8))) short short8;
typedef __attribute__((ext_vector_type(4))) float v4f;

__device__ __forceinline__ float bf2f(unsigned short u) {
    unsigned int x = ((unsigned int)u) << 16;
    float f; __builtin_memcpy(&f, &x, 4); return f;
}
__device__ __forceinline__ unsigned short f2bf(float f) {
    unsigned int x; __builtin_memcpy(&x, &f, 4);
    x += 0x7fffu + ((x >> 16) & 1u);   // RNE
    return (unsigned short)(x >> 16);
}

// ---------- prep: 3 jobs in one dispatch (unchanged, proven) ----------
__global__ void k_prep(const float* __restrict__ feat, const float* __restrict__ pos,
                       const float* __restrict__ theta, const float* __restrict__ pbias,
                       unsigned short* __restrict__ ft, float4* __restrict__ pt,
                       unsigned short* __restrict__ tbf) {
    __shared__ float tile[64][65];
    const int bid = blockIdx.x;
    if (bid < 512) {
        int b = bid >> 7, n0 = (bid & 127) << 6;
        int lane = threadIdx.x & 63, w = threadIdx.x >> 6;
#pragma unroll
        for (int r = 0; r < 16; ++r) {
            int i = (r << 2) | w;
            tile[i][lane] = feat[(b*DIN_ + i)*NPT + n0 + lane];
        }
        __syncthreads();
#pragma unroll
        for (int r = 0; r < 16; ++r) {
            int n = (r << 2) | w;
            ft[((size_t)(b*NPT + n0 + n))*DIN_ + lane] = f2bf(tile[lane][n]);
        }
    } else if (bid < 640) {
        int t = (bid - 512)*256 + threadIdx.x;   // 0..32767
        int b = t >> 13, n = t & 8191;
        float4 v;
        v.x = pos[(b*3 + 0)*NPT + n];
        v.y = pos[(b*3 + 1)*NPT + n];
        v.z = pos[(b*3 + 2)*NPT + n];
        v.w = 1.0f;
        pt[t] = v;
    } else {
        int e = (bid - 640)*256 + threadIdx.x;   // 0..2047
        int o = e >> 5, g = e & 31;
        short8 u;
#pragma unroll
        for (int j = 0; j < 8; ++j) {
            int c = g*8 + j;
            float v = (c < 192) ? theta[c*64 + o] : pbias[(c - 192)*64 + o];
            u[j] = (short)f2bf(v);
        }
        *reinterpret_cast<short8*>(tbf + o*256 + g*8) = u;   // 16B aligned
    }
}

// ---------- main: R6 structure + depth-16 explicit gather pipeline ----------
// R6 won by dropping redundant pt VMEM instrs (~12cy/instr). Remaining cost
// model: L3-latency-bound gathers with per-wave MLP ~4 (unroll-4 depth).
// This round: issue ALL 16 ft gathers of a pass into registers (two
// statically-indexed ushort4 banks, 32 VGPRs) BEFORE any FMA -> per-wave
// in-flight misses 4 -> 8..16. Everything else identical to R6.
template<bool USE_WS>
__global__ __launch_bounds__(256, 4) void k_main(
    const float*          __restrict__ feat,
    const float*          __restrict__ pos,
    const int*            __restrict__ nbr,
    const float*          __restrict__ theta,
    const float*          __restrict__ pbias,
    const float*          __restrict__ fbias,
    const unsigned short* __restrict__ ft,
    const float4*         __restrict__ pt,
    const unsigned short* __restrict__ tbf,
    float*                __restrict__ out)
{
    __shared__ __align__(16) unsigned short Xt[32*CPAD];  // 16896 B  [q][c]
    __shared__ int    nbs[KN*32];                         // 2048 B   [k][q]
    __shared__ float4 pcs[32];                            // 512 B
    __shared__ float4 ptk[32][16];                        // 8192 B   [q][k]
    // total 27648 B -> 4 blocks/CU

    const int tid  = threadIdx.x;
    const int lane = tid & 63;
    const int w    = tid >> 6;
    const int j16  = lane & 15;
    const int pt2  = lane >> 4;    // stage1: which of 4 points; epilogue: quad (kg)

    const int base = blockIdx.x << 5;   // 32 points/block; 8192%32==0 -> single batch
    const int b    = base >> 13;
    const int nb0  = base & 8191;

    // ---- cooperative preamble: nbr slab + center positions ----
#pragma unroll
    for (int r = 0; r < 2; ++r) {
        int idx = tid + (r << 8);            // 0..511
        int k = idx >> 5, c = idx & 31;
        nbs[idx] = nbr[(b*KN + k)*NPT + nb0 + c];
    }
    if (tid < 128) {
        if (USE_WS) {
            ((float*)pcs)[tid] = ((const float*)(pt + b*NPT + nb0))[tid];
        } else if (tid < 32) {
            int n = nb0 + tid;
            pcs[tid] = make_float4(pos[(b*3+0)*NPT + n], pos[(b*3+1)*NPT + n],
                                   pos[(b*3+2)*NPT + n], 1.0f);
        }
    }
    __syncthreads();

    const unsigned short* ftb = ft + (((size_t)b) << 19);   // b*NPT*64
    const float4*         ptb = pt + b*NPT;

    // ---- stage 1: 2 passes x 4 points per wave; lane owns (point, 4-feature chunk) ----
#pragma unroll
    for (int pass = 0; pass < 2; ++pass) {
        const int q = (w << 3) + (pass << 2) + pt2;
        const float4 pc = pcs[q];

        float acc[4][4];
#pragma unroll
        for (int p = 0; p < 4; ++p)
#pragma unroll
            for (int j = 0; j < 4; ++j) acc[p][j] = 0.f;

        if (USE_WS) {
            // pt dedup (R6, proven): lane (pt2 -> q, j16 -> k) loads pt once.
            const int idp = nbs[(j16 << 5) + q];
            ptk[q][j16] = ptb[idp];

            // depth-16 gather pipeline: issue ALL ft loads before any FMA.
            // Static indexing only (banks A/B) -> stays in VGPRs.
            ushort4 frA[8], frB[8];
#pragma unroll
            for (int k = 0; k < 8; ++k) {
                const int id = nbs[(k << 5) + q];
                frA[k] = *reinterpret_cast<const ushort4*>(
                    ftb + (((size_t)id) << 6) + (j16 << 2));
            }
#pragma unroll
            for (int k = 0; k < 8; ++k) {
                const int id = nbs[((k + 8) << 5) + q];
                frB[k] = *reinterpret_cast<const ushort4*>(
                    ftb + (((size_t)id) << 6) + (j16 << 2));
            }
#pragma unroll
            for (int k = 0; k < 8; ++k) {
                const float4 pg = ptk[q][k];
                float f[4] = { bf2f(frA[k].x), bf2f(frA[k].y),
                               bf2f(frA[k].z), bf2f(frA[k].w) };
#pragma unroll
                for (int j = 0; j < 4; ++j) {
                    acc[0][j] += pg.x * f[j];
                    acc[1][j] += pg.y * f[j];
                    acc[2][j] += pg.z * f[j];
                    acc[3][j] += f[j];
                }
            }
#pragma unroll
            for (int k = 0; k < 8; ++k) {
                const float4 pg = ptk[q][k + 8];
                float f[4] = { bf2f(frB[k].x), bf2f(frB[k].y),
                               bf2f(frB[k].z), bf2f(frB[k].w) };
#pragma unroll
                for (int j = 0; j < 4; ++j) {
                    acc[0][j] += pg.x * f[j];
                    acc[1][j] += pg.y * f[j];
                    acc[2][j] += pg.z * f[j];
                    acc[3][j] += f[j];
                }
            }
        } else {
#pragma unroll 4
            for (int k = 0; k < KN; ++k) {
                const int id = nbs[(k << 5) + q];
                float4 pg; float f[4];
                pg.x = pos[(b*3+0)*NPT + id];
                pg.y = pos[(b*3+1)*NPT + id];
                pg.z = pos[(b*3+2)*NPT + id];
                pg.w = 1.0f;
#pragma unroll
                for (int j = 0; j < 4; ++j)
                    f[j] = feat[(b*DIN_ + (j16<<2) + j)*NPT + id];
#pragma unroll
                for (int j = 0; j < 4; ++j) {
                    acc[0][j] += pg.x * f[j];
                    acc[1][j] += pg.y * f[j];
                    acc[2][j] += pg.z * f[j];
                    acc[3][j] += f[j];
                }
            }
        }
        // center correction: M_p -= pc_p * S
#pragma unroll
        for (int j = 0; j < 4; ++j) {
            acc[0][j] -= pc.x * acc[3][j];
            acc[1][j] -= pc.y * acc[3][j];
            acc[2][j] -= pc.z * acc[3][j];
        }
        // write X[q][c], c = p*64 + j16*4 + j  (bf16)
#pragma unroll
        for (int p = 0; p < 4; ++p) {
            ushort4 pk;
            pk.x = f2bf(acc[p][0]); pk.y = f2bf(acc[p][1]);
            pk.z = f2bf(acc[p][2]); pk.w = f2bf(acc[p][3]);
            *reinterpret_cast<ushort4*>(&Xt[q*CPAD + (p<<6) + (j16<<2)]) = pk;
        }
    }
    __syncthreads();

    // ---- epilogue: wave w -> o-rows [16w,16w+16); A-frags straight from L2-hot tbf ----
    const int kg   = pt2;                 // mfma quad
    const int orow = (w << 4) + j16;      // A: m = lane&15
    v4f acc0 = {0.f,0.f,0.f,0.f}, acc1 = {0.f,0.f,0.f,0.f};
#pragma unroll
    for (int ks = 0; ks < 8; ++ks) {
        const int koff = (ks << 5) + (kg << 3);   // k = quad*8 + j
        short8 a;
        if (USE_WS) {
            a = *reinterpret_cast<const short8*>(tbf + orow*256 + koff);
        } else {
#pragma unroll
            for (int j = 0; j < 8; ++j) {
                int c = koff + j;
                float v = (c < 192) ? theta[c*64 + orow] : pbias[(c - 192)*64 + orow];
                a[j] = (short)f2bf(v);
            }
        }
        short8 b0 = *reinterpret_cast<const short8*>(&Xt[j16*CPAD + koff]);
        short8 b1 = *reinterpret_cast<const short8*>(&Xt[(16 + j16)*CPAD + koff]);
        acc0 = __builtin_amdgcn_mfma_f32_16x16x32_bf16(a, b0, acc0, 0, 0, 0);
        acc1 = __builtin_amdgcn_mfma_f32_16x16x32_bf16(a, b1, acc1, 0, 0, 0);
    }
    // C/D: col=lane&15 (point), row=quad*4+reg (o)
#pragma unroll
    for (int r = 0; r < 4; ++r) {
        const int o = (w << 4) + (kg << 2) + r;
        const float fb = fbias[o];
        const size_t rowoff = (size_t)(b*DOUT_ + o)*NPT + nb0;
        out[rowoff + j16]      = acc0[r] + fb;
        out[rowoff + 16 + j16] = acc1[r] + fb;
    }
}

extern "C" void kernel_launch(void* const* d_in, const int* in_sizes, int n_in,
                              void* d_out, int out_size, void* d_ws, size_t ws_size,
                              hipStream_t stream) {
    const float* feat  = (const float*)d_in[0];
    const float* pos   = (const float*)d_in[1];
    const int*   nbr   = (const int*)d_in[2];
    const float* theta = (const float*)d_in[3];
    const float* pbias = (const float*)d_in[4];
    const float* fbias = (const float*)d_in[5];
    float* out = (float*)d_out;

    const size_t ft_bytes  = (size_t)NB*NPT*DIN_*2;          // 4 MiB
    const size_t pt_bytes  = (size_t)NB*NPT*sizeof(float4);  // 512 KiB
    const size_t tbf_bytes = (size_t)DOUT_*256*2;            // 32 KiB
    const int n_blocks = (NB*NPT)/32;                        // 1024

    if (ws_size >= ft_bytes + pt_bytes + tbf_bytes) {
        unsigned short* ft  = (unsigned short*)d_ws;
        float4*         pt  = (float4*)((char*)d_ws + ft_bytes);
        unsigned short* tbf = (unsigned short*)((char*)d_ws + ft_bytes + pt_bytes);
        k_prep<<<648, 256, 0, stream>>>(feat, pos, theta, pbias, ft, pt, tbf);
        k_main<true><<<n_blocks, 256, 0, stream>>>(feat, pos, nbr, theta, pbias, fbias,
                                                   ft, pt, tbf, out);
    } else {
        k_main<false><<<n_blocks, 256, 0, stream>>>(feat, pos, nbr, theta, pbias, fbias,
                                                    (const unsigned short*)feat,
                                                    (const float4*)feat,
                                                    (const unsigned short*)feat, out);
    }
}

// Round 8
// 82.010 us; speedup vs baseline: 1.5616x; 1.0535x over previous
//
#include <hip/hip_runtime.h>

#define NB    4
#define DIN_  64
#define DOUT_ 64
#define KN    16
#define NPT   8192
#define CPAD  264   // 256 c-entries + 8 pad shorts; rows 528B (16B-aligned)

typedef __attribute__((ext_vector_type(8))) short short8;
typedef __attribute__((ext_vector_type(4))) float v4f;

__device__ __forceinline__ float bf2f(unsigned short u) {
    unsigned int x = ((unsigned int)u) << 16;
    float f; __builtin_memcpy(&f, &x, 4); return f;
}
__device__ __forceinline__ unsigned short f2bf(float f) {
    unsigned int x; __builtin_memcpy(&x, &f, 4);
    x += 0x7fffu + ((x >> 16) & 1u);   // RNE
    return (unsigned short)(x >> 16);
}

// ---------- prep: 3 jobs in one dispatch ----------
// blocks [0,512):  feat fp32 [B][64][N] -> ft bf16 [B][N][64]
// blocks [512,640): pos fp32 [B][3][N]  -> pt float4 (x,y,z,1)
// blocks [640,648): theta/pbias -> tbs bf16, EPILOGUE-LANE-ORDER swizzled:
//   tbs[((w*8+ks)*64 + lane)*8 + j] = T[orow=w*16+(lane&15)][c=ks*32+(lane>>4)*8+j]
//   (c<192 -> theta[c][orow], else pbias[c-192][orow]) -> epilogue loads are
//   contiguous 1KB/wave-inst instead of 16 strided lines.
__global__ void k_prep(const float* __restrict__ feat, const float* __restrict__ pos,
                       const float* __restrict__ theta, const float* __restrict__ pbias,
                       unsigned short* __restrict__ ft, float4* __restrict__ pt,
                       unsigned short* __restrict__ tbs) {
    __shared__ float tile[64][65];
    const int bid = blockIdx.x;
    if (bid < 512) {
        int b = bid >> 7, n0 = (bid & 127) << 6;
        int lane = threadIdx.x & 63, w = threadIdx.x >> 6;
#pragma unroll
        for (int r = 0; r < 16; ++r) {
            int i = (r << 2) | w;
            tile[i][lane] = feat[(b*DIN_ + i)*NPT + n0 + lane];
        }
        __syncthreads();
#pragma unroll
        for (int r = 0; r < 16; ++r) {
            int n = (r << 2) | w;
            ft[((size_t)(b*NPT + n0 + n))*DIN_ + lane] = f2bf(tile[lane][n]);
        }
    } else if (bid < 640) {
        int t = (bid - 512)*256 + threadIdx.x;   // 0..32767
        int b = t >> 13, n = t & 8191;
        float4 v;
        v.x = pos[(b*3 + 0)*NPT + n];
        v.y = pos[(b*3 + 1)*NPT + n];
        v.z = pos[(b*3 + 2)*NPT + n];
        v.w = 1.0f;
        pt[t] = v;
    } else {
        int e = (bid - 640)*256 + threadIdx.x;   // 0..2047 = [w][ks][lane]
        int w  = e >> 9;
        int ks = (e >> 6) & 7;
        int ln = e & 63;
        int orow = (w << 4) + (ln & 15);
        int koff = (ks << 5) + ((ln >> 4) << 3);
        short8 u;
#pragma unroll
        for (int j = 0; j < 8; ++j) {
            int c = koff + j;
            float v = (c < 192) ? theta[c*64 + orow] : pbias[(c - 192)*64 + orow];
            u[j] = (short)f2bf(v);
        }
        *reinterpret_cast<short8*>(tbs + (size_t)e*8) = u;   // 16B aligned
    }
}

// ---------- main: R7 structure + swizzled A-frags + full-line out stores ----------
template<bool USE_WS>
__global__ __launch_bounds__(256, 4) void k_main(
    const float*          __restrict__ feat,
    const float*          __restrict__ pos,
    const int*            __restrict__ nbr,
    const float*          __restrict__ theta,
    const float*          __restrict__ pbias,
    const float*          __restrict__ fbias,
    const unsigned short* __restrict__ ft,
    const float4*         __restrict__ pt,
    const unsigned short* __restrict__ tbs,
    float*                __restrict__ out)
{
    __shared__ __align__(16) unsigned short Xt[32*CPAD];  // 16896 B  [q][c]
    __shared__ int    nbs[KN*32];                         // 2048 B   [k][q]
    __shared__ float4 pcs[32];                            // 512 B
    __shared__ float4 ptk[32][16];                        // 8192 B   [q][k]
    __shared__ __align__(16) float out_s[64][32];         // 8192 B   [o][n]
    // total 35840 B -> 4 blocks/CU (<= 40 KiB/block)

    const int tid  = threadIdx.x;
    const int lane = tid & 63;
    const int w    = tid >> 6;
    const int j16  = lane & 15;
    const int pt2  = lane >> 4;    // stage1: which of 4 points; epilogue: quad (kg)

    const int base = blockIdx.x << 5;   // 32 points/block; 8192%32==0 -> single batch
    const int b    = base >> 13;
    const int nb0  = base & 8191;

    // ---- cooperative preamble: nbr slab + center positions ----
#pragma unroll
    for (int r = 0; r < 2; ++r) {
        int idx = tid + (r << 8);            // 0..511
        int k = idx >> 5, c = idx & 31;
        nbs[idx] = nbr[(b*KN + k)*NPT + nb0 + c];
    }
    if (tid < 128) {
        if (USE_WS) {
            ((float*)pcs)[tid] = ((const float*)(pt + b*NPT + nb0))[tid];
        } else if (tid < 32) {
            int n = nb0 + tid;
            pcs[tid] = make_float4(pos[(b*3+0)*NPT + n], pos[(b*3+1)*NPT + n],
                                   pos[(b*3+2)*NPT + n], 1.0f);
        }
    }
    __syncthreads();

    const unsigned short* ftb = ft + (((size_t)b) << 19);   // b*NPT*64
    const float4*         ptb = pt + b*NPT;

    // ---- stage 1: 2 passes x 4 points per wave; lane owns (point, 4-feature chunk) ----
#pragma unroll
    for (int pass = 0; pass < 2; ++pass) {
        const int q = (w << 3) + (pass << 2) + pt2;
        const float4 pc = pcs[q];

        float acc[4][4];
#pragma unroll
        for (int p = 0; p < 4; ++p)
#pragma unroll
            for (int j = 0; j < 4; ++j) acc[p][j] = 0.f;

        if (USE_WS) {
            // pt dedup (R6): lane (pt2 -> q, j16 -> k) loads pt once.
            const int idp = nbs[(j16 << 5) + q];
            ptk[q][j16] = ptb[idp];

            // depth-16 gather pipeline (R7): all ft loads issued before any FMA.
            ushort4 frA[8], frB[8];
#pragma unroll
            for (int k = 0; k < 8; ++k) {
                const int id = nbs[(k << 5) + q];
                frA[k] = *reinterpret_cast<const ushort4*>(
                    ftb + (((size_t)id) << 6) + (j16 << 2));
            }
#pragma unroll
            for (int k = 0; k < 8; ++k) {
                const int id = nbs[((k + 8) << 5) + q];
                frB[k] = *reinterpret_cast<const ushort4*>(
                    ftb + (((size_t)id) << 6) + (j16 << 2));
            }
#pragma unroll
            for (int k = 0; k < 8; ++k) {
                const float4 pg = ptk[q][k];
                float f[4] = { bf2f(frA[k].x), bf2f(frA[k].y),
                               bf2f(frA[k].z), bf2f(frA[k].w) };
#pragma unroll
                for (int j = 0; j < 4; ++j) {
                    acc[0][j] += pg.x * f[j];
                    acc[1][j] += pg.y * f[j];
                    acc[2][j] += pg.z * f[j];
                    acc[3][j] += f[j];
                }
            }
#pragma unroll
            for (int k = 0; k < 8; ++k) {
                const float4 pg = ptk[q][k + 8];
                float f[4] = { bf2f(frB[k].x), bf2f(frB[k].y),
                               bf2f(frB[k].z), bf2f(frB[k].w) };
#pragma unroll
                for (int j = 0; j < 4; ++j) {
                    acc[0][j] += pg.x * f[j];
                    acc[1][j] += pg.y * f[j];
                    acc[2][j] += pg.z * f[j];
                    acc[3][j] += f[j];
                }
            }
        } else {
#pragma unroll 4
            for (int k = 0; k < KN; ++k) {
                const int id = nbs[(k << 5) + q];
                float4 pg; float f[4];
                pg.x = pos[(b*3+0)*NPT + id];
                pg.y = pos[(b*3+1)*NPT + id];
                pg.z = pos[(b*3+2)*NPT + id];
                pg.w = 1.0f;
#pragma unroll
                for (int j = 0; j < 4; ++j)
                    f[j] = feat[(b*DIN_ + (j16<<2) + j)*NPT + id];
#pragma unroll
                for (int j = 0; j < 4; ++j) {
                    acc[0][j] += pg.x * f[j];
                    acc[1][j] += pg.y * f[j];
                    acc[2][j] += pg.z * f[j];
                    acc[3][j] += f[j];
                }
            }
        }
        // center correction: M_p -= pc_p * S
#pragma unroll
        for (int j = 0; j < 4; ++j) {
            acc[0][j] -= pc.x * acc[3][j];
            acc[1][j] -= pc.y * acc[3][j];
            acc[2][j] -= pc.z * acc[3][j];
        }
        // write X[q][c], c = p*64 + j16*4 + j  (bf16)
#pragma unroll
        for (int p = 0; p < 4; ++p) {
            ushort4 pk;
            pk.x = f2bf(acc[p][0]); pk.y = f2bf(acc[p][1]);
            pk.z = f2bf(acc[p][2]); pk.w = f2bf(acc[p][3]);
            *reinterpret_cast<ushort4*>(&Xt[q*CPAD + (p<<6) + (j16<<2)]) = pk;
        }
    }
    __syncthreads();

    // ---- epilogue: wave w -> o-rows [16w,16w+16); A-frags from swizzled tbs ----
    const int kg   = pt2;                 // mfma quad
    const int orow = (w << 4) + j16;      // A: m = lane&15
    v4f acc0 = {0.f,0.f,0.f,0.f}, acc1 = {0.f,0.f,0.f,0.f};
#pragma unroll
    for (int ks = 0; ks < 8; ++ks) {
        const int koff = (ks << 5) + (kg << 3);   // k = quad*8 + j
        short8 a;
        if (USE_WS) {
            // contiguous: 64 lanes x 16B = 1KB segment per inst
            a = *reinterpret_cast<const short8*>(
                tbs + ((size_t)(((w << 3) + ks) << 6) + lane) * 8);
        } else {
#pragma unroll
            for (int j = 0; j < 8; ++j) {
                int c = koff + j;
                float v = (c < 192) ? theta[c*64 + orow] : pbias[(c - 192)*64 + orow];
                a[j] = (short)f2bf(v);
            }
        }
        short8 b0 = *reinterpret_cast<const short8*>(&Xt[j16*CPAD + koff]);
        short8 b1 = *reinterpret_cast<const short8*>(&Xt[(16 + j16)*CPAD + koff]);
        acc0 = __builtin_amdgcn_mfma_f32_16x16x32_bf16(a, b0, acc0, 0, 0, 0);
        acc1 = __builtin_amdgcn_mfma_f32_16x16x32_bf16(a, b1, acc1, 0, 0, 0);
    }
    // C/D: col=lane&15 (point), row=quad*4+reg (o). Stage to LDS, then write
    // FULL 128B lines (one o-row's 32 floats = exactly one cache line) ->
    // kills the 8MB read-for-ownership over-fetch seen in R4's FETCH_SIZE.
#pragma unroll
    for (int r = 0; r < 4; ++r) {
        const int o = (w << 4) + (kg << 2) + r;
        const float fb = fbias[o];
        out_s[o][j16]      = acc0[r] + fb;
        out_s[o][16 + j16] = acc1[r] + fb;
    }
    __syncthreads();
#pragma unroll
    for (int rep = 0; rep < 2; ++rep) {
        const int c  = tid + (rep << 8);     // 0..511 float4-chunks
        const int o  = c >> 3, seg = c & 7;
        const float4 v = *reinterpret_cast<const float4*>(&out_s[o][seg << 2]);
        *reinterpret_cast<float4*>(
            &out[(size_t)(b*DOUT_ + o)*NPT + nb0 + (seg << 2)]) = v;
    }
}

extern "C" void kernel_launch(void* const* d_in, const int* in_sizes, int n_in,
                              void* d_out, int out_size, void* d_ws, size_t ws_size,
                              hipStream_t stream) {
    const float* feat  = (const float*)d_in[0];
    const float* pos   = (const float*)d_in[1];
    const int*   nbr   = (const int*)d_in[2];
    const float* theta = (const float*)d_in[3];
    const float* pbias = (const float*)d_in[4];
    const float* fbias = (const float*)d_in[5];
    float* out = (float*)d_out;

    const size_t ft_bytes  = (size_t)NB*NPT*DIN_*2;          // 4 MiB
    const size_t pt_bytes  = (size_t)NB*NPT*sizeof(float4);  // 512 KiB
    const size_t tbs_bytes = (size_t)DOUT_*256*2;            // 32 KiB
    const int n_blocks = (NB*NPT)/32;                        // 1024

    if (ws_size >= ft_bytes + pt_bytes + tbs_bytes) {
        unsigned short* ft  = (unsigned short*)d_ws;
        float4*         pt  = (float4*)((char*)d_ws + ft_bytes);
        unsigned short* tbs = (unsigned short*)((char*)d_ws + ft_bytes + pt_bytes);
        k_prep<<<648, 256, 0, stream>>>(feat, pos, theta, pbias, ft, pt, tbs);
        k_main<true><<<n_blocks, 256, 0, stream>>>(feat, pos, nbr, theta, pbias, fbias,
                                                   ft, pt, tbs, out);
    } else {
        k_main<false><<<n_blocks, 256, 0, stream>>>(feat, pos, nbr, theta, pbias, fbias,
                                                    (const unsigned short*)feat,
                                                    (const float4*)feat,
                                                    (const unsigned short*)feat, out);
    }
}